// Round 1
// baseline (53.863 us; speedup 1.0000x reference)
//
#include <hip/hip_runtime.h>

#define Bn 32
#define Ln 4096
#define Cn 4
#define GROUPn 4
#define NFG (Bn / GROUPn)
#define EPSf 1e-8f
#define JS_EPSf 1e-7f

// Block-wide sum reduction. Valid result in thread 0. Uses sm[4].
__device__ __forceinline__ float blockReduceSum(float v, float* sm) {
    #pragma unroll
    for (int off = 32; off > 0; off >>= 1)
        v += __shfl_down(v, off, 64);
    int lane = threadIdx.x & 63;
    int wid  = threadIdx.x >> 6;
    if (lane == 0) sm[wid] = v;
    __syncthreads();
    int nw = blockDim.x >> 6;
    v = (threadIdx.x < nw) ? sm[threadIdx.x] : 0.0f;
    if (wid == 0) {
        #pragma unroll
        for (int off = 32; off > 0; off >>= 1)
            v += __shfl_down(v, off, 64);
    }
    return v;
}

__device__ __forceinline__ int argmax4(float4 y) {
    int lbl = 0; float best = y.x;
    if (y.y > best) { best = y.y; lbl = 1; }
    if (y.z > best) { best = y.z; lbl = 2; }
    if (y.w > best) { best = y.w; lbl = 3; }
    return lbl;
}

// CE sum (acc[0], accumulates -logp so ce_loss = acc[0]) and raw r2 sum (acc[1]).
__global__ void imp_loss_ce_r2(const float* __restrict__ logits,
                               const float* __restrict__ prob,
                               const float* __restrict__ y_true,
                               float* __restrict__ acc) {
    __shared__ float sm[4];
    float ce = 0.0f;
    const int n1 = Bn * Ln;
    for (int idx = blockIdx.x * blockDim.x + threadIdx.x; idx < n1;
         idx += gridDim.x * blockDim.x) {
        float4 y = ((const float4*)y_true)[idx];
        float4 x = ((const float4*)logits)[idx];
        int lbl = argmax4(y);
        float mx = fmaxf(fmaxf(x.x, x.y), fmaxf(x.z, x.w));
        float se = expf(x.x - mx) + expf(x.y - mx) + expf(x.z - mx) + expf(x.w - mx);
        float xl = (lbl == 0) ? x.x : (lbl == 1) ? x.y : (lbl == 2) ? x.z : x.w;
        ce += (mx + logf(se)) - xl;   // = -log_softmax(x)[lbl]
    }

    float r2 = 0.0f;
    const int n2 = NFG * Ln;
    for (int idx = blockIdx.x * blockDim.x + threadIdx.x; idx < n2;
         idx += gridDim.x * blockDim.x) {
        int g = idx >> 12;          // / Ln
        int l = idx & (Ln - 1);
        int cnt = 0;
        float palt[GROUPn];
        #pragma unroll
        for (int j = 0; j < GROUPn; ++j) {
            int b = g * GROUPn + j;
            float4 y = ((const float4*)y_true)[b * Ln + l];
            cnt += (argmax4(y) != 0);
            float4 p = ((const float4*)prob)[b * Ln + l];
            palt[j] = p.y + p.z + p.w;
        }
        if (cnt > 0 && cnt < GROUPn) {
            float af = (float)cnt * 0.25f;
            float denom = af * (1.0f - af);   // >= 0.1875, clamp at 0.01 never binds
            float s = 0.0f;
            #pragma unroll
            for (int j = 0; j < GROUPn; ++j) { float d = palt[j] - af; s += d * d; }
            r2 += 0.25f * s / denom;
        }
    }

    float cesum = blockReduceSum(ce, sm);
    __syncthreads();
    float r2sum = blockReduceSum(r2, sm);
    if (threadIdx.x == 0) {
        atomicAdd(&acc[0], cesum);
        atomicAdd(&acc[1], r2sum);
    }
}

// Pairwise JS * evo weight, accumulated into acc[2].
// One block per ordered pair; only i<j does work, using js symmetry:
// sum_ij w_ij*js_ij = sum_{i<j} (w_ij + w_ji)*js_ij  (diagonal js == 0 exactly).
__global__ void imp_loss_evo(const float* __restrict__ prob,
                             const float* __restrict__ y_true,
                             const float* __restrict__ y_evo,
                             float* __restrict__ acc) {
    int i = blockIdx.x >> 5;   // / Bn
    int j = blockIdx.x & 31;
    if (i >= j) return;        // uniform across block

    __shared__ float sm[4];
    __shared__ float wpair;
    if (threadIdx.x == 0) {
        float si = 0.0f, sj = 0.0f;
        for (int k = 0; k < Bn; ++k) {
            si += expf(-y_evo[i * Bn + k]);
            sj += expf(-y_evo[j * Bn + k]);
        }
        float wij = expf(-y_evo[i * Bn + j]) / (si + EPSf);
        float wji = expf(-y_evo[j * Bn + i]) / (sj + EPSf);
        wpair = wij + wji;
    }
    __syncthreads();

    const float4* pi = (const float4*)prob   + i * Ln;
    const float4* pj = (const float4*)prob   + j * Ln;
    const float4* yi = (const float4*)y_true + i * Ln;
    const float4* yj = (const float4*)y_true + j * Ln;

    float js = 0.0f;
    for (int l = threadIdx.x; l < Ln; l += blockDim.x) {
        float4 a = yi[l], b = yj[l];
        // exact one-hot rows: elementwise equality == label equality
        bool eq = (a.x == b.x) && (a.y == b.y) && (a.z == b.z) && (a.w == b.w);
        if (eq) {
            float4 p = pi[l], q = pj[l];
            float s = 0.0f;
            {
                float m = 0.5f * (p.x + q.x); float lm = logf(m + JS_EPSf);
                s += p.x * (logf(p.x + JS_EPSf) - lm) + q.x * (logf(q.x + JS_EPSf) - lm);
            }
            {
                float m = 0.5f * (p.y + q.y); float lm = logf(m + JS_EPSf);
                s += p.y * (logf(p.y + JS_EPSf) - lm) + q.y * (logf(q.y + JS_EPSf) - lm);
            }
            {
                float m = 0.5f * (p.z + q.z); float lm = logf(m + JS_EPSf);
                s += p.z * (logf(p.z + JS_EPSf) - lm) + q.z * (logf(q.z + JS_EPSf) - lm);
            }
            {
                float m = 0.5f * (p.w + q.w); float lm = logf(m + JS_EPSf);
                s += p.w * (logf(p.w + JS_EPSf) - lm) + q.w * (logf(q.w + JS_EPSf) - lm);
            }
            js += 0.5f * s;
        }
    }

    float t = blockReduceSum(js, sm);
    if (threadIdx.x == 0) atomicAdd(&acc[2], wpair * t);
}

__global__ void imp_loss_finalize(const float* __restrict__ acc,
                                  float* __restrict__ out) {
    float ce = acc[0];
    float r2_loss = -acc[1] * (float)GROUPn / (float)Bn;
    float evo = acc[2];
    out[0] = ce + r2_loss + evo;
    out[1] = ce;
    out[2] = r2_loss;
    out[3] = evo;
}

extern "C" void kernel_launch(void* const* d_in, const int* in_sizes, int n_in,
                              void* d_out, int out_size, void* d_ws, size_t ws_size,
                              hipStream_t stream) {
    const float* logits = (const float*)d_in[0];
    const float* prob   = (const float*)d_in[1];
    const float* y_true = (const float*)d_in[2];
    const float* y_evo  = (const float*)d_in[3];
    float* out = (float*)d_out;
    float* acc = (float*)d_ws;

    hipMemsetAsync(acc, 0, 4 * sizeof(float), stream);
    hipLaunchKernelGGL(imp_loss_ce_r2, dim3(256), dim3(256), 0, stream,
                       logits, prob, y_true, acc);
    hipLaunchKernelGGL(imp_loss_evo, dim3(Bn * Bn), dim3(256), 0, stream,
                       prob, y_true, y_evo, acc);
    hipLaunchKernelGGL(imp_loss_finalize, dim3(1), dim3(1), 0, stream, acc, out);
}

// Round 2
// 38.404 us; speedup vs baseline: 1.4025x; 1.4025x over previous
//
#include <hip/hip_runtime.h>

#define Bn 32
#define Ln 4096
#define Cn 4
#define GROUPn 4
#define NFG (Bn / GROUPn)
#define EPSf 1e-8f
#define JS_EPSf 1e-7f
#define NBLK 1024
#define NTHR 256

// Block-wide sum reduction. Valid result in thread 0. Uses sm[4].
__device__ __forceinline__ float blockReduceSum(float v, float* sm) {
    #pragma unroll
    for (int off = 32; off > 0; off >>= 1)
        v += __shfl_down(v, off, 64);
    int lane = threadIdx.x & 63;
    int wid  = threadIdx.x >> 6;
    if (lane == 0) sm[wid] = v;
    __syncthreads();
    int nw = blockDim.x >> 6;
    v = (threadIdx.x < nw) ? sm[threadIdx.x] : 0.0f;
    if (wid == 0) {
        #pragma unroll
        for (int off = 32; off > 0; off >>= 1)
            v += __shfl_down(v, off, 64);
    }
    return v;
}

__device__ __forceinline__ int argmax4(float4 y) {
    int lbl = 0; float best = y.x;
    if (y.y > best) { best = y.y; lbl = 1; }
    if (y.z > best) { best = y.z; lbl = 2; }
    if (y.w > best) { best = y.w; lbl = 3; }
    return lbl;
}

// One fused kernel: 1024 blocks.
//  - Pair part: block b -> (i=b>>5, j=b&31); active iff i<j. Uses js symmetry:
//    sum_ij w_ij*js_ij = sum_{i<j} (w_ij+w_ji)*js_ij (diagonal js==0 exactly).
//  - CE part: grid-stride over B*L rows.
//  - R2 part: grid-stride over NFG*L items.
// Each block stores 3 partials with plain stores (no zero-init, no atomics).
__global__ void imp_fused(const float* __restrict__ logits,
                          const float* __restrict__ prob,
                          const float* __restrict__ y_true,
                          const float* __restrict__ y_evo,
                          float* __restrict__ pce,
                          float* __restrict__ pr2,
                          float* __restrict__ pevo) {
    __shared__ float sm[4];
    const int tid = blockIdx.x * blockDim.x + threadIdx.x;
    const int nthreads = gridDim.x * blockDim.x;

    // ---- CE ----
    float ce = 0.0f;
    for (int idx = tid; idx < Bn * Ln; idx += nthreads) {
        float4 y = ((const float4*)y_true)[idx];
        float4 x = ((const float4*)logits)[idx];
        int lbl = argmax4(y);
        float mx = fmaxf(fmaxf(x.x, x.y), fmaxf(x.z, x.w));
        float se = __expf(x.x - mx) + __expf(x.y - mx) +
                   __expf(x.z - mx) + __expf(x.w - mx);
        float xl = (lbl == 0) ? x.x : (lbl == 1) ? x.y : (lbl == 2) ? x.z : x.w;
        ce += (mx + __logf(se)) - xl;   // = -log_softmax(x)[lbl]
    }

    // ---- R2 ----
    float r2 = 0.0f;
    for (int idx = tid; idx < NFG * Ln; idx += nthreads) {
        int g = idx >> 12;          // / Ln
        int l = idx & (Ln - 1);
        int cnt = 0;
        float palt[GROUPn];
        #pragma unroll
        for (int j = 0; j < GROUPn; ++j) {
            int b = g * GROUPn + j;
            float4 y = ((const float4*)y_true)[b * Ln + l];
            cnt += (argmax4(y) != 0);
            float4 p = ((const float4*)prob)[b * Ln + l];
            palt[j] = p.y + p.z + p.w;
        }
        if (cnt > 0 && cnt < GROUPn) {
            float af = (float)cnt * 0.25f;
            float denom = af * (1.0f - af);   // >= 0.1875; 0.01 clamp never binds
            float s = 0.0f;
            #pragma unroll
            for (int j = 0; j < GROUPn; ++j) { float d = palt[j] - af; s += d * d; }
            r2 += 0.25f * s / denom;
        }
    }

    // ---- Evo / JS pair ----
    const int i = blockIdx.x >> 5;
    const int j = blockIdx.x & 31;
    const bool active = (i < j);
    float js = 0.0f;
    float wpair = 0.0f;
    if (active) {
        if (threadIdx.x == 0) {
            float si = 0.0f, sj = 0.0f;
            for (int k = 0; k < Bn; ++k) {
                si += __expf(-y_evo[i * Bn + k]);
                sj += __expf(-y_evo[j * Bn + k]);
            }
            wpair = __expf(-y_evo[i * Bn + j]) / (si + EPSf)
                  + __expf(-y_evo[j * Bn + i]) / (sj + EPSf);
        }
        const float4* pi = (const float4*)prob   + i * Ln;
        const float4* pj = (const float4*)prob   + j * Ln;
        const float4* yi = (const float4*)y_true + i * Ln;
        const float4* yj = (const float4*)y_true + j * Ln;
        for (int l = threadIdx.x; l < Ln; l += blockDim.x) {
            float4 a = yi[l], b = yj[l];
            // exact one-hot rows: elementwise equality == label equality
            bool eq = (a.x == b.x) && (a.y == b.y) && (a.z == b.z) && (a.w == b.w);
            if (eq) {
                float4 p = pi[l], q = pj[l];
                float s = 0.0f;
                {
                    float m = 0.5f * (p.x + q.x); float lm = __logf(m + JS_EPSf);
                    s += p.x * (__logf(p.x + JS_EPSf) - lm) + q.x * (__logf(q.x + JS_EPSf) - lm);
                }
                {
                    float m = 0.5f * (p.y + q.y); float lm = __logf(m + JS_EPSf);
                    s += p.y * (__logf(p.y + JS_EPSf) - lm) + q.y * (__logf(q.y + JS_EPSf) - lm);
                }
                {
                    float m = 0.5f * (p.z + q.z); float lm = __logf(m + JS_EPSf);
                    s += p.z * (__logf(p.z + JS_EPSf) - lm) + q.z * (__logf(q.z + JS_EPSf) - lm);
                }
                {
                    float m = 0.5f * (p.w + q.w); float lm = __logf(m + JS_EPSf);
                    s += p.w * (__logf(p.w + JS_EPSf) - lm) + q.w * (__logf(q.w + JS_EPSf) - lm);
                }
                js += 0.5f * s;
            }
        }
    }

    float s1 = blockReduceSum(ce, sm);
    __syncthreads();
    float s2 = blockReduceSum(r2, sm);
    __syncthreads();
    float s3 = blockReduceSum(js, sm);
    if (threadIdx.x == 0) {
        pce[blockIdx.x]  = s1;
        pr2[blockIdx.x]  = s2;
        pevo[blockIdx.x] = active ? wpair * s3 : 0.0f;
    }
}

// Final reduction of 3 x NBLK partials + loss assembly. One block.
__global__ void imp_reduce(const float* __restrict__ pce,
                           const float* __restrict__ pr2,
                           const float* __restrict__ pevo,
                           float* __restrict__ out) {
    __shared__ float sm[4];
    float ce = 0.0f, r2 = 0.0f, evo = 0.0f;
    for (int idx = threadIdx.x; idx < NBLK; idx += blockDim.x) {
        ce  += pce[idx];
        r2  += pr2[idx];
        evo += pevo[idx];
    }
    ce = blockReduceSum(ce, sm);
    __syncthreads();
    r2 = blockReduceSum(r2, sm);
    __syncthreads();
    evo = blockReduceSum(evo, sm);
    if (threadIdx.x == 0) {
        float r2_loss = -r2 * (float)GROUPn / (float)Bn;
        out[0] = ce + r2_loss + evo;
        out[1] = ce;
        out[2] = r2_loss;
        out[3] = evo;
    }
}

extern "C" void kernel_launch(void* const* d_in, const int* in_sizes, int n_in,
                              void* d_out, int out_size, void* d_ws, size_t ws_size,
                              hipStream_t stream) {
    const float* logits = (const float*)d_in[0];
    const float* prob   = (const float*)d_in[1];
    const float* y_true = (const float*)d_in[2];
    const float* y_evo  = (const float*)d_in[3];
    float* out  = (float*)d_out;
    float* pce  = (float*)d_ws;
    float* pr2  = pce + NBLK;
    float* pevo = pr2 + NBLK;

    hipLaunchKernelGGL(imp_fused, dim3(NBLK), dim3(NTHR), 0, stream,
                       logits, prob, y_true, y_evo, pce, pr2, pevo);
    hipLaunchKernelGGL(imp_reduce, dim3(1), dim3(NTHR), 0, stream,
                       pce, pr2, pevo, out);
}